// Round 5
// baseline (1400.919 us; speedup 1.0000x reference)
//
#include <hip/hip_runtime.h>

#define BN 16384
#define TT 128
#define MM 4
#define SS 12
#define BLOCK 64
#define NSER (BLOCK / 4)    // 16 series per block (one wave)
#define TSTRIDE 145         // doubles per series transpose region

// Single-wave workgroup. LDS ops from one wave are processed in order by the
// LDS pipe, so the cross-lane transpose needs no s_barrier / lgkmcnt(0) drain;
// wave_barrier() only pins compiler instruction order at the hazard points.

__global__ __launch_bounds__(BLOCK, 1) void kf_kernel(
    const float* __restrict__ inp,   // [B][T][M]
    const float* __restrict__ Fm,    // [S][S]
    const float* __restrict__ Hm,    // [M][S]
    const float* __restrict__ Qm,    // [S][S]
    const float* __restrict__ Rm,    // [M][M]
    const float* __restrict__ m0p,   // [B][S]
    const float* __restrict__ P0p,   // [B][S][S]
    float* __restrict__ outp)        // [T][B][M]
{
    __shared__ double Fd[SS * SS];
    __shared__ double tb[NSER * TSTRIDE];

    const int tid  = threadIdx.x;
    const int gid  = blockIdx.x * BLOCK + tid;
    const int b    = gid >> 2;        // series
    const int c    = gid & 3;         // quad sub-lane: owns P cols/rows {3c,3c+1,3c+2}
    const int sb   = tid >> 2;        // series-in-block
    const int col0 = 3 * c;

    for (int i = tid; i < SS * SS; i += BLOCK) Fd[i] = (double)Fm[i];

    // wave-uniform constants cached in registers (VGPRs are free at 1 wave/SIMD)
    double Hf[MM][SS];   // full H
#pragma unroll
    for (int n = 0; n < MM; ++n)
#pragma unroll
        for (int s = 0; s < SS; ++s) Hf[n][s] = (double)Hm[n * SS + s];

    double Hc[MM][3];    // own 3 columns of H
#pragma unroll
    for (int n = 0; n < MM; ++n)
#pragma unroll
        for (int jj = 0; jj < 3; ++jj) Hc[n][jj] = (double)Hm[n * SS + col0 + jj];

    double Rs[10];       // upper triangle of R
    {
        int u = 0;
#pragma unroll
        for (int n = 0; n < MM; ++n)
#pragma unroll
            for (int t2 = 0; t2 < MM; ++t2)
                if (t2 >= n) Rs[u++] = (double)Rm[n * MM + t2];
    }

    double Qc[SS][3];    // own 3 columns of Q
#pragma unroll
    for (int s = 0; s < SS; ++s)
#pragma unroll
        for (int jj = 0; jj < 3; ++jj) Qc[s][jj] = (double)Qm[s * SS + col0 + jj];

    // persistent per-lane state: full mean + own 3 columns of symmetric P
    double m[SS];
#pragma unroll
    for (int s = 0; s < SS; ++s) m[s] = (double)m0p[b * SS + s];

    double P[SS][3];
#pragma unroll
    for (int s = 0; s < SS; ++s)
#pragma unroll
        for (int jj = 0; jj < 3; ++jj)
            P[s][jj] = (double)P0p[b * SS * SS + s * SS + col0 + jj];

    const float* op = inp + b * (TT * MM) + c;  // own measurement stream
    float obn = op[0];
    double* tser = &tb[sb * TSTRIDE];

    __syncthreads();  // F in LDS ready (once, outside the loop)

#pragma unroll 1
    for (int t = 0; t < TT; ++t) {
        __builtin_amdgcn_wave_barrier();  // order: prev Ur reads before new writes
        // ---------- GEMM1: U-row i = F[i,:]*P(local cols) -> LDS ----------
#pragma unroll
        for (int i = 0; i < SS; ++i) {
            double fr[SS];
#pragma unroll
            for (int s = 0; s < SS; ++s) fr[s] = Fd[i * SS + s];
            double u0 = 0.0, u1 = 0.0, u2 = 0.0;
#pragma unroll
            for (int s = 0; s < SS; ++s) {
                u0 += fr[s] * P[s][0];
                u1 += fr[s] * P[s][1];
                u2 += fr[s] * P[s][2];
            }
            tser[i * SS + col0 + 0] = u0;
            tser[i * SS + col0 + 1] = u1;
            tser[i * SS + col0 + 2] = u2;
        }

        // ---------- own 3 rows of predicted mean: mvl[jj] = F[3c+jj,:] . m ----------
        double mvl[3];
#pragma unroll
        for (int jj = 0; jj < 3; ++jj) {
            double a = 0.0;
#pragma unroll
            for (int s = 0; s < SS; ++s) a += Fd[(col0 + jj) * SS + s] * m[s];
            mvl[jj] = a;
        }

        __builtin_amdgcn_wave_barrier();  // order: writes before Ur reads (HW LDS FIFO)

        // ---------- GEMM2 (split-K): P <- Q + U * F^T  (prior cov, in place) -------
#pragma unroll
        for (int h = 0; h < 2; ++h) {
            double Ur[3][6];
#pragma unroll
            for (int jj = 0; jj < 3; ++jj)
#pragma unroll
                for (int kk = 0; kk < 6; ++kk)
                    Ur[jj][kk] = tser[(col0 + jj) * SS + h * 6 + kk];
#pragma unroll
            for (int s = 0; s < SS; ++s) {
                double fr6[6];
#pragma unroll
                for (int kk = 0; kk < 6; ++kk) fr6[kk] = Fd[s * SS + h * 6 + kk];
                double p0 = (h == 0) ? Qc[s][0] : P[s][0];
                double p1 = (h == 0) ? Qc[s][1] : P[s][1];
                double p2 = (h == 0) ? Qc[s][2] : P[s][2];
#pragma unroll
                for (int kk = 0; kk < 6; ++kk) {
                    p0 += Ur[0][kk] * fr6[kk];
                    p1 += Ur[1][kk] * fr6[kk];
                    p2 += Ur[2][kk] * fr6[kk];
                }
                P[s][0] = p0; P[s][1] = p1; P[s][2] = p2;
            }
        }

        // ---------- y[n] via quad butterfly of partials ----------
        double y[MM];
#pragma unroll
        for (int n = 0; n < MM; ++n) {
            double py = Hc[n][0] * mvl[0] + Hc[n][1] * mvl[1] + Hc[n][2] * mvl[2];
            py += __shfl_xor(py, 1, 4);
            py += __shfl_xor(py, 2, 4);
            y[n] = py;
        }
        double ysel = (c & 2) ? ((c & 1) ? y[3] : y[2]) : ((c & 1) ? y[1] : y[0]);
        outp[t * (BN * MM) + b * MM + c] = (float)ysel;

        float obc = obn;
        if (t + 1 < TT) obn = op[(t + 1) * MM];  // prefetch next obs

        // residuals all-local (obs shared by 4 cheap b32 shuffles)
        double r[MM];
#pragma unroll
        for (int n = 0; n < MM; ++n)
            r[n] = (double)__shfl(obc, n, 4) - y[n];

        // ---------- HP = H * P_prior (local cols) ----------
        double HPl[MM][3];
#pragma unroll
        for (int n = 0; n < MM; ++n) {
            double h0 = 0.0, h1 = 0.0, h2 = 0.0;
#pragma unroll
            for (int s = 0; s < SS; ++s) {
                double hv = Hf[n][s];
                h0 += hv * P[s][0]; h1 += hv * P[s][1]; h2 += hv * P[s][2];
            }
            HPl[n][0] = h0; HPl[n][1] = h1; HPl[n][2] = h2;
        }

        // ---------- innovation cov: local partial + quad butterfly ----------
        double Su[10];
        {
            int u = 0;
#pragma unroll
            for (int n = 0; n < MM; ++n)
#pragma unroll
                for (int t2 = 0; t2 < MM; ++t2) {
                    if (t2 < n) continue;
                    double acc = HPl[n][0] * Hc[t2][0]
                               + HPl[n][1] * Hc[t2][1]
                               + HPl[n][2] * Hc[t2][2];
                    acc += __shfl_xor(acc, 1, 4);
                    acc += __shfl_xor(acc, 2, 4);
                    Su[u] = acc + Rs[u];
                    ++u;
                }
        }
        double s00 = Su[0], s01 = Su[1], s02 = Su[2], s03 = Su[3];
        double s11 = Su[4], s12 = Su[5], s13 = Su[6];
        double s22 = Su[7], s23 = Su[8], s33 = Su[9];

        // ---------- symmetric 4x4 inverse via 2x2 Schur (fp64) ----------
        double ra   = 1.0 / (s00 * s11 - s01 * s01);
        double ai00 = s11 * ra, ai01 = -s01 * ra, ai11 = s00 * ra;
        double w00 = ai00 * s02 + ai01 * s12;
        double w01 = ai00 * s03 + ai01 * s13;
        double w10 = ai01 * s02 + ai11 * s12;
        double w11 = ai01 * s03 + ai11 * s13;
        double e00 = s22 - (s02 * w00 + s12 * w10);
        double e01 = s23 - (s02 * w01 + s12 * w11);
        double e11 = s33 - (s03 * w01 + s13 * w11);
        double rmm = 1.0 / (e00 * e11 - e01 * e01);
        double q22 = e11 * rmm, q23 = -e01 * rmm, q33 = e00 * rmm;
        double x00 = w00 * q22 + w01 * q23;
        double x01 = w00 * q23 + w01 * q33;
        double x10 = w10 * q22 + w11 * q23;
        double x11 = w10 * q23 + w11 * q33;
        double q00 = ai00 + x00 * w00 + x01 * w01;
        double q01 = ai01 + x00 * w10 + x01 * w11;
        double q11 = ai11 + x10 * w10 + x11 * w11;
        double Qi[MM][MM] = {
            { q00,  q01,  -x00, -x01 },
            { q01,  q11,  -x10, -x11 },
            { -x00, -x10,  q22,  q23 },
            { -x01, -x11,  q23,  q33 }
        };

        // ---------- z = Sinv r ; mean update (no K materialized) ----------
        double z0 = Qi[0][0] * r[0] + Qi[0][1] * r[1] + Qi[0][2] * r[2] + Qi[0][3] * r[3];
        double z1 = Qi[1][0] * r[0] + Qi[1][1] * r[1] + Qi[1][2] * r[2] + Qi[1][3] * r[3];
        double z2 = Qi[2][0] * r[0] + Qi[2][1] * r[1] + Qi[2][2] * r[2] + Qi[2][3] * r[3];
        double z3 = Qi[3][0] * r[0] + Qi[3][1] * r[1] + Qi[3][2] * r[2] + Qi[3][3] * r[3];

        double upd[3];
#pragma unroll
        for (int jj = 0; jj < 3; ++jj)
            upd[jj] = HPl[0][jj] * z0 + HPl[1][jj] * z1
                    + HPl[2][jj] * z2 + HPl[3][jj] * z3;

        // all-gather posterior mean: state k lives on lane k/3 as mvl[k%3]+upd[k%3]
#pragma unroll
        for (int k = 0; k < SS; ++k)
            m[k] = __shfl(mvl[k % 3] + upd[k % 3], k / 3, 4);

        // ---------- covariance update: P -= (HP)^T Sinv (HP) ----------
        double G[MM][3];  // G = Sinv * HP (local cols)
#pragma unroll
        for (int n = 0; n < MM; ++n)
#pragma unroll
            for (int jj = 0; jj < 3; ++jj)
                G[n][jj] = Qi[n][0] * HPl[0][jj] + Qi[n][1] * HPl[1][jj]
                         + Qi[n][2] * HPl[2][jj] + Qi[n][3] * HPl[3][jj];

#pragma unroll
        for (int s = 0; s < SS; ++s) {
            double h0 = __shfl(HPl[0][s % 3], s / 3, 4);
            double h1 = __shfl(HPl[1][s % 3], s / 3, 4);
            double h2 = __shfl(HPl[2][s % 3], s / 3, 4);
            double h3 = __shfl(HPl[3][s % 3], s / 3, 4);
#pragma unroll
            for (int jj = 0; jj < 3; ++jj)
                P[s][jj] -= h0 * G[0][jj] + h1 * G[1][jj]
                          + h2 * G[2][jj] + h3 * G[3][jj];
        }
    }
}

extern "C" void kernel_launch(void* const* d_in, const int* in_sizes, int n_in,
                              void* d_out, int out_size, void* d_ws, size_t ws_size,
                              hipStream_t stream) {
    const float* inp = (const float*)d_in[0];
    const float* F   = (const float*)d_in[1];
    const float* H   = (const float*)d_in[2];
    const float* Q   = (const float*)d_in[3];
    const float* R   = (const float*)d_in[4];
    const float* m0  = (const float*)d_in[5];
    const float* P0  = (const float*)d_in[6];
    float* out = (float*)d_out;

    dim3 grid((BN * MM) / BLOCK), block(BLOCK);
    hipLaunchKernelGGL(kf_kernel, grid, block, 0, stream,
                       inp, F, H, Q, R, m0, P0, out);
}

// Round 6
// 934.851 us; speedup vs baseline: 1.4985x; 1.4985x over previous
//
#include <hip/hip_runtime.h>

#define BN 16384
#define TT 128
#define MM 4
#define SS 12
#define BLOCK 64
#define NSER (BLOCK / 4)    // 16 series per block (one wave)
#define TSTRIDE 146         // doubles per series region; 146*8=1168B, 16B-aligned

// Single-wave workgroup. LDS ops from one wave are processed in order by the
// LDS pipe, so the cross-lane transpose needs no s_barrier / lgkmcnt(0) drain;
// wave_barrier() only pins compiler instruction order at the hazard points.
// (Correctness of this scheme was verified in R5: absmax identical to R4.)

__global__ __launch_bounds__(BLOCK, 1) void kf_kernel(
    const float* __restrict__ inp,   // [B][T][M]
    const float* __restrict__ Fm,    // [S][S]
    const float* __restrict__ Hm,    // [M][S]
    const float* __restrict__ Qm,    // [S][S]
    const float* __restrict__ Rm,    // [M][M]
    const float* __restrict__ m0p,   // [B][S]
    const float* __restrict__ P0p,   // [B][S][S]
    float* __restrict__ outp)        // [T][B][M]
{
    __shared__ double Fd[SS * SS];
    __shared__ double Hd[MM * SS];
    __shared__ double Qd[SS * SS];
    __shared__ double Rd[MM * MM];
    __shared__ double tb[NSER * TSTRIDE];

    const int tid  = threadIdx.x;
    const int gid  = blockIdx.x * BLOCK + tid;
    const int b    = gid >> 2;        // series
    const int c    = gid & 3;        // quad sub-lane: owns P cols/rows {3c,3c+1,3c+2}
    const int sb   = tid >> 2;        // series-in-block
    const int col0 = 3 * c;

    for (int i = tid; i < SS * SS; i += BLOCK) {
        Fd[i] = (double)Fm[i];
        Qd[i] = (double)Qm[i];
    }
    if (tid < MM * SS) Hd[tid] = (double)Hm[tid];
    if (tid < MM * MM) Rd[tid] = (double)Rm[tid];

    // persistent per-lane state: full mean + own 3 columns of symmetric P
    double m[SS];
#pragma unroll
    for (int s = 0; s < SS; ++s) m[s] = (double)m0p[b * SS + s];

    double P[SS][3];
#pragma unroll
    for (int s = 0; s < SS; ++s)
#pragma unroll
        for (int jj = 0; jj < 3; ++jj)
            P[s][jj] = (double)P0p[b * SS * SS + s * SS + col0 + jj];

    const float* op = inp + b * (TT * MM) + c;  // own measurement stream
    float obn = op[0];
    double* tser = &tb[sb * TSTRIDE];

    __syncthreads();  // constants in LDS ready (once, outside the loop)

#pragma unroll 1
    for (int t = 0; t < TT; ++t) {
        __builtin_amdgcn_wave_barrier();  // order: prev Ur reads before new writes
        // ---------- GEMM1: U-row i = F[i,:]*P(local cols) -> LDS ----------
#pragma unroll
        for (int i = 0; i < SS; ++i) {
            double fr[SS];
#pragma unroll
            for (int s = 0; s < SS; ++s) fr[s] = Fd[i * SS + s];
            double u0 = 0.0, u1 = 0.0, u2 = 0.0;
#pragma unroll
            for (int s = 0; s < SS; ++s) {
                u0 += fr[s] * P[s][0];
                u1 += fr[s] * P[s][1];
                u2 += fr[s] * P[s][2];
            }
            tser[i * SS + col0 + 0] = u0;
            tser[i * SS + col0 + 1] = u1;
            tser[i * SS + col0 + 2] = u2;
        }

        // ---------- own 3 rows of predicted mean: mvl[jj] = F[3c+jj,:] . m ----------
        double mvl[3];
#pragma unroll
        for (int jj = 0; jj < 3; ++jj) {
            double a = 0.0;
#pragma unroll
            for (int s = 0; s < SS; ++s) a += Fd[(col0 + jj) * SS + s] * m[s];
            mvl[jj] = a;
        }

        __builtin_amdgcn_wave_barrier();  // order: writes before Ur reads (HW LDS FIFO)

        // ---------- GEMM2 (split-K): P <- Q + U * F^T  (prior cov, in place) -------
#pragma unroll
        for (int h = 0; h < 2; ++h) {
            double Ur[3][6];
#pragma unroll
            for (int jj = 0; jj < 3; ++jj)
#pragma unroll
                for (int kk = 0; kk < 6; ++kk)
                    Ur[jj][kk] = tser[(col0 + jj) * SS + h * 6 + kk];
#pragma unroll
            for (int s = 0; s < SS; ++s) {
                double fr6[6];
#pragma unroll
                for (int kk = 0; kk < 6; ++kk) fr6[kk] = Fd[s * SS + h * 6 + kk];
                double p0 = (h == 0) ? Qd[s * SS + col0 + 0] : P[s][0];
                double p1 = (h == 0) ? Qd[s * SS + col0 + 1] : P[s][1];
                double p2 = (h == 0) ? Qd[s * SS + col0 + 2] : P[s][2];
#pragma unroll
                for (int kk = 0; kk < 6; ++kk) {
                    p0 += Ur[0][kk] * fr6[kk];
                    p1 += Ur[1][kk] * fr6[kk];
                    p2 += Ur[2][kk] * fr6[kk];
                }
                P[s][0] = p0; P[s][1] = p1; P[s][2] = p2;
            }
        }

        // ---------- y[n] via quad butterfly of partials ----------
        double y[MM];
#pragma unroll
        for (int n = 0; n < MM; ++n) {
            double py = Hd[n * SS + col0 + 0] * mvl[0]
                      + Hd[n * SS + col0 + 1] * mvl[1]
                      + Hd[n * SS + col0 + 2] * mvl[2];
            py += __shfl_xor(py, 1, 4);
            py += __shfl_xor(py, 2, 4);
            y[n] = py;
        }
        double ysel = (c & 2) ? ((c & 1) ? y[3] : y[2]) : ((c & 1) ? y[1] : y[0]);
        outp[t * (BN * MM) + b * MM + c] = (float)ysel;

        float obc = obn;
        if (t + 1 < TT) obn = op[(t + 1) * MM];  // prefetch next obs

        // residuals all-local (obs shared by 4 cheap b32 shuffles)
        double r[MM];
#pragma unroll
        for (int n = 0; n < MM; ++n)
            r[n] = (double)__shfl(obc, n, 4) - y[n];

        // ---------- HP = H * P_prior (local cols) ----------
        double HPl[MM][3];
#pragma unroll
        for (int n = 0; n < MM; ++n) {
            double h0 = 0.0, h1 = 0.0, h2 = 0.0;
#pragma unroll
            for (int s = 0; s < SS; ++s) {
                double hv = Hd[n * SS + s];
                h0 += hv * P[s][0]; h1 += hv * P[s][1]; h2 += hv * P[s][2];
            }
            HPl[n][0] = h0; HPl[n][1] = h1; HPl[n][2] = h2;
        }

        // ---------- innovation cov: local partial + quad butterfly ----------
        double Su[10];
        {
            int u = 0;
#pragma unroll
            for (int n = 0; n < MM; ++n)
#pragma unroll
                for (int t2 = 0; t2 < MM; ++t2) {
                    if (t2 < n) continue;
                    double acc = HPl[n][0] * Hd[t2 * SS + col0 + 0]
                               + HPl[n][1] * Hd[t2 * SS + col0 + 1]
                               + HPl[n][2] * Hd[t2 * SS + col0 + 2];
                    acc += __shfl_xor(acc, 1, 4);
                    acc += __shfl_xor(acc, 2, 4);
                    Su[u] = acc + Rd[n * MM + t2];
                    ++u;
                }
        }
        double s00 = Su[0], s01 = Su[1], s02 = Su[2], s03 = Su[3];
        double s11 = Su[4], s12 = Su[5], s13 = Su[6];
        double s22 = Su[7], s23 = Su[8], s33 = Su[9];

        // ---------- symmetric 4x4 inverse via 2x2 Schur (fp64) ----------
        double ra   = 1.0 / (s00 * s11 - s01 * s01);
        double ai00 = s11 * ra, ai01 = -s01 * ra, ai11 = s00 * ra;
        double w00 = ai00 * s02 + ai01 * s12;
        double w01 = ai00 * s03 + ai01 * s13;
        double w10 = ai01 * s02 + ai11 * s12;
        double w11 = ai01 * s03 + ai11 * s13;
        double e00 = s22 - (s02 * w00 + s12 * w10);
        double e01 = s23 - (s02 * w01 + s12 * w11);
        double e11 = s33 - (s03 * w01 + s13 * w11);
        double rmm = 1.0 / (e00 * e11 - e01 * e01);
        double q22 = e11 * rmm, q23 = -e01 * rmm, q33 = e00 * rmm;
        double x00 = w00 * q22 + w01 * q23;
        double x01 = w00 * q23 + w01 * q33;
        double x10 = w10 * q22 + w11 * q23;
        double x11 = w10 * q23 + w11 * q33;
        double q00 = ai00 + x00 * w00 + x01 * w01;
        double q01 = ai01 + x00 * w10 + x01 * w11;
        double q11 = ai11 + x10 * w10 + x11 * w11;
        double Qi[MM][MM] = {
            { q00,  q01,  -x00, -x01 },
            { q01,  q11,  -x10, -x11 },
            { -x00, -x10,  q22,  q23 },
            { -x01, -x11,  q23,  q33 }
        };

        // ---------- z = Sinv r ; mean update (no K materialized) ----------
        double z0 = Qi[0][0] * r[0] + Qi[0][1] * r[1] + Qi[0][2] * r[2] + Qi[0][3] * r[3];
        double z1 = Qi[1][0] * r[0] + Qi[1][1] * r[1] + Qi[1][2] * r[2] + Qi[1][3] * r[3];
        double z2 = Qi[2][0] * r[0] + Qi[2][1] * r[1] + Qi[2][2] * r[2] + Qi[2][3] * r[3];
        double z3 = Qi[3][0] * r[0] + Qi[3][1] * r[1] + Qi[3][2] * r[2] + Qi[3][3] * r[3];

        double upd[3];
#pragma unroll
        for (int jj = 0; jj < 3; ++jj)
            upd[jj] = HPl[0][jj] * z0 + HPl[1][jj] * z1
                    + HPl[2][jj] * z2 + HPl[3][jj] * z3;

        // all-gather posterior mean: state k lives on lane k/3 as mvl[k%3]+upd[k%3]
#pragma unroll
        for (int k = 0; k < SS; ++k)
            m[k] = __shfl(mvl[k % 3] + upd[k % 3], k / 3, 4);

        // ---------- covariance update: P -= (HP)^T Sinv (HP) ----------
        double G[MM][3];  // G = Sinv * HP (local cols)
#pragma unroll
        for (int n = 0; n < MM; ++n)
#pragma unroll
            for (int jj = 0; jj < 3; ++jj)
                G[n][jj] = Qi[n][0] * HPl[0][jj] + Qi[n][1] * HPl[1][jj]
                         + Qi[n][2] * HPl[2][jj] + Qi[n][3] * HPl[3][jj];

#pragma unroll
        for (int s = 0; s < SS; ++s) {
            double h0 = __shfl(HPl[0][s % 3], s / 3, 4);
            double h1 = __shfl(HPl[1][s % 3], s / 3, 4);
            double h2 = __shfl(HPl[2][s % 3], s / 3, 4);
            double h3 = __shfl(HPl[3][s % 3], s / 3, 4);
#pragma unroll
            for (int jj = 0; jj < 3; ++jj)
                P[s][jj] -= h0 * G[0][jj] + h1 * G[1][jj]
                          + h2 * G[2][jj] + h3 * G[3][jj];
        }
    }
}

extern "C" void kernel_launch(void* const* d_in, const int* in_sizes, int n_in,
                              void* d_out, int out_size, void* d_ws, size_t ws_size,
                              hipStream_t stream) {
    const float* inp = (const float*)d_in[0];
    const float* F   = (const float*)d_in[1];
    const float* H   = (const float*)d_in[2];
    const float* Q   = (const float*)d_in[3];
    const float* R   = (const float*)d_in[4];
    const float* m0  = (const float*)d_in[5];
    const float* P0  = (const float*)d_in[6];
    float* out = (float*)d_out;

    dim3 grid((BN * MM) / BLOCK), block(BLOCK);
    hipLaunchKernelGGL(kf_kernel, grid, block, 0, stream,
                       inp, F, H, Q, R, m0, P0, out);
}

// Round 8
// 790.433 us; speedup vs baseline: 1.7723x; 1.1827x over previous
//
#include <hip/hip_runtime.h>

#define BN 16384
#define TT 128
#define MM 4
#define SS 12
#define BLOCK 64
#define NSER (BLOCK / 4)    // 16 series per block (one wave)
#define TSTRIDE 145         // doubles per series region (R4-measured best banking)

// Single-wave workgroup; all cross-lane ops are within aligned lane-quads and
// use DPP quad_perm on the VALU pipe (no LDS/ds_bpermute). The only LDS
// cross-lane is the U-transpose; same-wave LDS ordering makes it safe with
// compiler-order fences (verified R5/R6: absmax identical to __syncthreads).

// quad_perm ctrl: broadcast from sub-lane R -> R*0x55; xor1 -> 0xB1; xor2 -> 0x4E
template<int CTRL>
__device__ __forceinline__ float dpp32(float v) {
    union { int i; float f; } u, o;
    u.f = v;
    o.i = __builtin_amdgcn_update_dpp(0, u.i, CTRL, 0xF, 0xF, true);
    return o.f;
}
template<int CTRL>
__device__ __forceinline__ double dpp64(double v) {
    union { double d; int i[2]; } u, o;
    u.d = v;
    o.i[0] = __builtin_amdgcn_update_dpp(0, u.i[0], CTRL, 0xF, 0xF, true);
    o.i[1] = __builtin_amdgcn_update_dpp(0, u.i[1], CTRL, 0xF, 0xF, true);
    return o.d;
}
__device__ __forceinline__ double qsum(double v) {  // sum over the quad
    v += dpp64<0xB1>(v);
    v += dpp64<0x4E>(v);
    return v;
}

__global__ __launch_bounds__(BLOCK, 1) void kf_kernel(
    const float* __restrict__ inp,   // [B][T][M]
    const float* __restrict__ Fm,    // [S][S]
    const float* __restrict__ Hm,    // [M][S]
    const float* __restrict__ Qm,    // [S][S]
    const float* __restrict__ Rm,    // [M][M]
    const float* __restrict__ m0p,   // [B][S]
    const float* __restrict__ P0p,   // [B][S][S]
    float* __restrict__ outp)        // [T][B][M]
{
    __shared__ double Fd[SS * SS];
    __shared__ double Hd[MM * SS];
    __shared__ double Qd[SS * SS];
    __shared__ double Rd[MM * MM];
    __shared__ double tb[NSER * TSTRIDE];

    const int tid  = threadIdx.x;
    const int gid  = blockIdx.x * BLOCK + tid;
    const int b    = gid >> 2;        // series
    const int c    = gid & 3;         // quad sub-lane: owns P cols/rows {3c,3c+1,3c+2}
    const int sb   = tid >> 2;        // series-in-block
    const int col0 = 3 * c;

    for (int i = tid; i < SS * SS; i += BLOCK) {
        Fd[i] = (double)Fm[i];
        Qd[i] = (double)Qm[i];
    }
    if (tid < MM * SS) Hd[tid] = (double)Hm[tid];
    if (tid < MM * MM) Rd[tid] = (double)Rm[tid];

    // persistent per-lane state: full mean + own 3 columns of symmetric P
    double m[SS];
#pragma unroll
    for (int s = 0; s < SS; ++s) m[s] = (double)m0p[b * SS + s];

    double P[SS][3];
#pragma unroll
    for (int s = 0; s < SS; ++s)
#pragma unroll
        for (int jj = 0; jj < 3; ++jj)
            P[s][jj] = (double)P0p[b * SS * SS + s * SS + col0 + jj];

    const float* op = inp + b * (TT * MM) + c;  // own measurement stream
    float obn = op[0];
    double* tser = &tb[sb * TSTRIDE];

    __syncthreads();  // constants in LDS ready (once, outside the loop)

#pragma unroll 1
    for (int t = 0; t < TT; ++t) {
        __builtin_amdgcn_wave_barrier();  // order: prev Ur reads before new writes
        // ---------- GEMM1: U-row i = F[i,:]*P(local cols) -> LDS ----------
#pragma unroll
        for (int i = 0; i < SS; ++i) {
            double fr[SS];
#pragma unroll
            for (int s = 0; s < SS; ++s) fr[s] = Fd[i * SS + s];
            double u0 = 0.0, u1 = 0.0, u2 = 0.0;
#pragma unroll
            for (int s = 0; s < SS; ++s) {
                u0 += fr[s] * P[s][0];
                u1 += fr[s] * P[s][1];
                u2 += fr[s] * P[s][2];
            }
            tser[i * SS + col0 + 0] = u0;
            tser[i * SS + col0 + 1] = u1;
            tser[i * SS + col0 + 2] = u2;
        }

        // ---------- own 3 rows of predicted mean: mvl[jj] = F[3c+jj,:] . m ----------
        double mvl[3];
#pragma unroll
        for (int jj = 0; jj < 3; ++jj) {
            double a = 0.0;
#pragma unroll
            for (int s = 0; s < SS; ++s) a += Fd[(col0 + jj) * SS + s] * m[s];
            mvl[jj] = a;
        }

        __builtin_amdgcn_wave_barrier();  // order: writes before Ur reads (HW LDS FIFO)

        // ---------- GEMM2 (split-K): P <- Q + U * F^T  (prior cov, in place) -------
#pragma unroll
        for (int h = 0; h < 2; ++h) {
            double Ur[3][6];
#pragma unroll
            for (int jj = 0; jj < 3; ++jj)
#pragma unroll
                for (int kk = 0; kk < 6; ++kk)
                    Ur[jj][kk] = tser[(col0 + jj) * SS + h * 6 + kk];
#pragma unroll
            for (int s = 0; s < SS; ++s) {
                double fr6[6];
#pragma unroll
                for (int kk = 0; kk < 6; ++kk) fr6[kk] = Fd[s * SS + h * 6 + kk];
                double p0 = (h == 0) ? Qd[s * SS + col0 + 0] : P[s][0];
                double p1 = (h == 0) ? Qd[s * SS + col0 + 1] : P[s][1];
                double p2 = (h == 0) ? Qd[s * SS + col0 + 2] : P[s][2];
#pragma unroll
                for (int kk = 0; kk < 6; ++kk) {
                    p0 += Ur[0][kk] * fr6[kk];
                    p1 += Ur[1][kk] * fr6[kk];
                    p2 += Ur[2][kk] * fr6[kk];
                }
                P[s][0] = p0; P[s][1] = p1; P[s][2] = p2;
            }
        }

        // ---------- y[n] via quad DPP butterfly of partials ----------
        double y[MM];
#pragma unroll
        for (int n = 0; n < MM; ++n) {
            double py = Hd[n * SS + col0 + 0] * mvl[0]
                      + Hd[n * SS + col0 + 1] * mvl[1]
                      + Hd[n * SS + col0 + 2] * mvl[2];
            y[n] = qsum(py);
        }
        double ysel = (c & 2) ? ((c & 1) ? y[3] : y[2]) : ((c & 1) ? y[1] : y[0]);
        outp[t * (BN * MM) + b * MM + c] = (float)ysel;

        float obc = obn;
        if (t + 1 < TT) obn = op[(t + 1) * MM];  // prefetch next obs

        // residuals all-local (obs shared by 4 cheap b32 DPP broadcasts)
        double r[MM];
        r[0] = (double)dpp32<0x00>(obc) - y[0];
        r[1] = (double)dpp32<0x55>(obc) - y[1];
        r[2] = (double)dpp32<0xAA>(obc) - y[2];
        r[3] = (double)dpp32<0xFF>(obc) - y[3];

        // ---------- HP = H * P_prior (local cols) ----------
        double HPl[MM][3];
#pragma unroll
        for (int n = 0; n < MM; ++n) {
            double h0 = 0.0, h1 = 0.0, h2 = 0.0;
#pragma unroll
            for (int s = 0; s < SS; ++s) {
                double hv = Hd[n * SS + s];
                h0 += hv * P[s][0]; h1 += hv * P[s][1]; h2 += hv * P[s][2];
            }
            HPl[n][0] = h0; HPl[n][1] = h1; HPl[n][2] = h2;
        }

        // ---------- innovation cov: local partial + quad DPP butterfly ----------
        double Su[10];
        {
            int u = 0;
#pragma unroll
            for (int n = 0; n < MM; ++n)
#pragma unroll
                for (int t2 = 0; t2 < MM; ++t2) {
                    if (t2 < n) continue;
                    double acc = HPl[n][0] * Hd[t2 * SS + col0 + 0]
                               + HPl[n][1] * Hd[t2 * SS + col0 + 1]
                               + HPl[n][2] * Hd[t2 * SS + col0 + 2];
                    Su[u] = qsum(acc) + Rd[n * MM + t2];
                    ++u;
                }
        }
        double s00 = Su[0], s01 = Su[1], s02 = Su[2], s03 = Su[3];
        double s11 = Su[4], s12 = Su[5], s13 = Su[6];
        double s22 = Su[7], s23 = Su[8], s33 = Su[9];

        // ---------- symmetric 4x4 inverse via 2x2 Schur (fp64) ----------
        double ra   = 1.0 / (s00 * s11 - s01 * s01);
        double ai00 = s11 * ra, ai01 = -s01 * ra, ai11 = s00 * ra;
        double w00 = ai00 * s02 + ai01 * s12;
        double w01 = ai00 * s03 + ai01 * s13;
        double w10 = ai01 * s02 + ai11 * s12;
        double w11 = ai01 * s03 + ai11 * s13;
        double e00 = s22 - (s02 * w00 + s12 * w10);
        double e01 = s23 - (s02 * w01 + s12 * w11);
        double e11 = s33 - (s03 * w01 + s13 * w11);
        double rmm = 1.0 / (e00 * e11 - e01 * e01);
        double q22 = e11 * rmm, q23 = -e01 * rmm, q33 = e00 * rmm;
        double x00 = w00 * q22 + w01 * q23;
        double x01 = w00 * q23 + w01 * q33;
        double x10 = w10 * q22 + w11 * q23;
        double x11 = w10 * q23 + w11 * q33;
        double q00 = ai00 + x00 * w00 + x01 * w01;
        double q01 = ai01 + x00 * w10 + x01 * w11;
        double q11 = ai11 + x10 * w10 + x11 * w11;
        double Qi[MM][MM] = {
            { q00,  q01,  -x00, -x01 },
            { q01,  q11,  -x10, -x11 },
            { -x00, -x10,  q22,  q23 },
            { -x01, -x11,  q23,  q33 }
        };

        // ---------- z = Sinv r ; mean update (no K materialized) ----------
        double z0 = Qi[0][0] * r[0] + Qi[0][1] * r[1] + Qi[0][2] * r[2] + Qi[0][3] * r[3];
        double z1 = Qi[1][0] * r[0] + Qi[1][1] * r[1] + Qi[1][2] * r[2] + Qi[1][3] * r[3];
        double z2 = Qi[2][0] * r[0] + Qi[2][1] * r[1] + Qi[2][2] * r[2] + Qi[2][3] * r[3];
        double z3 = Qi[3][0] * r[0] + Qi[3][1] * r[1] + Qi[3][2] * r[2] + Qi[3][3] * r[3];

        double pm[3];  // posterior mean, own 3 states
#pragma unroll
        for (int jj = 0; jj < 3; ++jj)
            pm[jj] = mvl[jj] + HPl[0][jj] * z0 + HPl[1][jj] * z1
                   + HPl[2][jj] * z2 + HPl[3][jj] * z3;

        // all-gather posterior mean via DPP broadcasts (state k lives on lane k/3)
        m[0]  = dpp64<0x00>(pm[0]);  m[1]  = dpp64<0x00>(pm[1]);  m[2]  = dpp64<0x00>(pm[2]);
        m[3]  = dpp64<0x55>(pm[0]);  m[4]  = dpp64<0x55>(pm[1]);  m[5]  = dpp64<0x55>(pm[2]);
        m[6]  = dpp64<0xAA>(pm[0]);  m[7]  = dpp64<0xAA>(pm[1]);  m[8]  = dpp64<0xAA>(pm[2]);
        m[9]  = dpp64<0xFF>(pm[0]);  m[10] = dpp64<0xFF>(pm[1]);  m[11] = dpp64<0xFF>(pm[2]);

        // ---------- covariance update: P -= (HP)^T Sinv (HP) ----------
        double G[MM][3];  // G = Sinv * HP (local cols)
#pragma unroll
        for (int n = 0; n < MM; ++n)
#pragma unroll
            for (int jj = 0; jj < 3; ++jj)
                G[n][jj] = Qi[n][0] * HPl[0][jj] + Qi[n][1] * HPl[1][jj]
                         + Qi[n][2] * HPl[2][jj] + Qi[n][3] * HPl[3][jj];

        // rows 3q+jr gathered from sub-lane q via DPP broadcast
#pragma unroll
        for (int jr = 0; jr < 3; ++jr) {
            {
                double h0 = dpp64<0x00>(HPl[0][jr]), h1 = dpp64<0x00>(HPl[1][jr]);
                double h2 = dpp64<0x00>(HPl[2][jr]), h3 = dpp64<0x00>(HPl[3][jr]);
#pragma unroll
                for (int jj = 0; jj < 3; ++jj)
                    P[jr][jj] -= h0 * G[0][jj] + h1 * G[1][jj] + h2 * G[2][jj] + h3 * G[3][jj];
            }
            {
                double h0 = dpp64<0x55>(HPl[0][jr]), h1 = dpp64<0x55>(HPl[1][jr]);
                double h2 = dpp64<0x55>(HPl[2][jr]), h3 = dpp64<0x55>(HPl[3][jr]);
#pragma unroll
                for (int jj = 0; jj < 3; ++jj)
                    P[3 + jr][jj] -= h0 * G[0][jj] + h1 * G[1][jj] + h2 * G[2][jj] + h3 * G[3][jj];
            }
            {
                double h0 = dpp64<0xAA>(HPl[0][jr]), h1 = dpp64<0xAA>(HPl[1][jr]);
                double h2 = dpp64<0xAA>(HPl[2][jr]), h3 = dpp64<0xAA>(HPl[3][jr]);
#pragma unroll
                for (int jj = 0; jj < 3; ++jj)
                    P[6 + jr][jj] -= h0 * G[0][jj] + h1 * G[1][jj] + h2 * G[2][jj] + h3 * G[3][jj];
            }
            {
                double h0 = dpp64<0xFF>(HPl[0][jr]), h1 = dpp64<0xFF>(HPl[1][jr]);
                double h2 = dpp64<0xFF>(HPl[2][jr]), h3 = dpp64<0xFF>(HPl[3][jr]);
#pragma unroll
                for (int jj = 0; jj < 3; ++jj)
                    P[9 + jr][jj] -= h0 * G[0][jj] + h1 * G[1][jj] + h2 * G[2][jj] + h3 * G[3][jj];
            }
        }
    }
}

extern "C" void kernel_launch(void* const* d_in, const int* in_sizes, int n_in,
                              void* d_out, int out_size, void* d_ws, size_t ws_size,
                              hipStream_t stream) {
    const float* inp = (const float*)d_in[0];
    const float* F   = (const float*)d_in[1];
    const float* H   = (const float*)d_in[2];
    const float* Q   = (const float*)d_in[3];
    const float* R   = (const float*)d_in[4];
    const float* m0  = (const float*)d_in[5];
    const float* P0  = (const float*)d_in[6];
    float* out = (float*)d_out;

    dim3 grid((BN * MM) / BLOCK), block(BLOCK);
    hipLaunchKernelGGL(kf_kernel, grid, block, 0, stream,
                       inp, F, H, Q, R, m0, P0, out);
}